// Round 10
// baseline (1553.365 us; speedup 1.0000x reference)
//
#include <hip/hip_runtime.h>
#include <hip/hip_bf16.h>

#define N_NODES 131072
#define N_GRAPHS 4096
#define D_Z 512
#define D_X 256
#define D_U 64
#define D_H 512
#define D_IN 768      // D_Z + D_X
#define KTOT 1280     // D_IN + D_H
#define NG1 1024      // two gates (Z,R) fused

using bf16   = __bf16;
using bf16x8 = __attribute__((ext_vector_type(8))) __bf16;
using f32x4  = __attribute__((ext_vector_type(4))) float;
using fl4    = __attribute__((ext_vector_type(4))) float;

__device__ __forceinline__ void gload_lds16(const void* g, void* lds) {
    __builtin_amdgcn_global_load_lds(
        (const __attribute__((address_space(1))) unsigned int*)g,
        (__attribute__((address_space(3))) unsigned int*)lds,
        16, 0, 0);
}

// ---------------- prep: weights -> bf16, transposed WT[n][k]; fused biases ---
__global__ void prep_weights(const float* __restrict__ Wxz, const float* __restrict__ Whz,
                             const float* __restrict__ Wxr, const float* __restrict__ Whr,
                             const float* __restrict__ Wxh, const float* __restrict__ Whh,
                             const float* __restrict__ bxz, const float* __restrict__ bhz,
                             const float* __restrict__ bxr, const float* __restrict__ bhr,
                             const float* __restrict__ bxh, const float* __restrict__ bhh,
                             bf16* __restrict__ WT1, bf16* __restrict__ WT2,
                             float* __restrict__ bias1, float* __restrict__ bias2)
{
    int idx = blockIdx.x * blockDim.x + threadIdx.x;
    if (idx < NG1)
        bias1[idx] = (idx < D_H) ? (bxz[idx] + bhz[idx]) : (bxr[idx - D_H] + bhr[idx - D_H]);
    if (idx < D_H)
        bias2[idx] = bxh[idx] + bhh[idx];

    const int T1 = NG1 * (KTOT / 8);
    if (idx < T1) {
        int n = idx % NG1, kc = idx / NG1, k0 = kc * 8;
        int col = (n < D_H) ? n : n - D_H;
        const float* Wx = (n < D_H) ? Wxz : Wxr;
        const float* Wh = (n < D_H) ? Whz : Whr;
        bf16x8 o;
        #pragma unroll
        for (int i = 0; i < 8; ++i) {
            int k = k0 + i;
            float f = (k < D_IN) ? Wx[(long)k * D_H + col] : Wh[(long)(k - D_IN) * D_H + col];
            o[i] = (bf16)f;
        }
        *(bf16x8*)(WT1 + (long)n * KTOT + k0) = o;
    } else {
        int j = idx - T1;               // [0, 512*160)
        int n = j % D_H, kc = j / D_H, k0 = kc * 8;
        bf16x8 o;
        #pragma unroll
        for (int i = 0; i < 8; ++i) {
            int k = k0 + i;
            float f = (k < D_IN) ? Wxh[(long)k * D_H + n] : Whh[(long)(k - D_IN) * D_H + n];
            o[i] = (bf16)f;
        }
        *(bf16x8*)(WT2 + (long)n * KTOT + k0) = o;
    }
}

// ---------------- prep: A = [z | x | prev_h] -> bf16 [N_NODES][1280] ---------
__global__ void prep_A(const float* __restrict__ z, const float* __restrict__ x,
                       const float* __restrict__ ph, bf16* __restrict__ Abf)
{
    long idx = (long)blockIdx.x * blockDim.x + threadIdx.x;   // N_NODES*160
    long row = idx / 160;
    int  e   = (int)(idx % 160) * 8;
    const float* src;
    if (e < D_Z)        src = z  + row * D_Z + e;
    else if (e < D_IN)  src = x  + row * D_X + (e - D_Z);
    else                src = ph + row * D_H + (e - D_IN);
    fl4 v0 = *(const fl4*)src;
    fl4 v1 = *(const fl4*)(src + 4);
    bf16x8 o;
    o[0]=(bf16)v0[0]; o[1]=(bf16)v0[1]; o[2]=(bf16)v0[2]; o[3]=(bf16)v0[3];
    o[4]=(bf16)v1[0]; o[5]=(bf16)v1[1]; o[6]=(bf16)v1[2]; o[7]=(bf16)v1[3];
    *(bf16x8*)(Abf + row * KTOT + e) = o;
}

// ----- GEMM 128x128, BK=64, 4 waves (2x2): A via LDS, B direct from L2 ------
// R10: LDS read port was saturated (64 b128/block/tile ~ 768cy; x3 blocks >
// tile-slot). Weights are 2.6 MB = permanently L2-resident -> load B frags
// global->VGPR (8 x 16B/lane/tile, bases loop-invariant), LDS stages A only
// (32 reads/block/tile). launch_bounds(256,3): 168-reg budget, no spill
// (acc 64 + Bfrag 32 + af 16 + addr ~ 130); LDS 16 KB.
// MODE 1: C=[Z|R] -> sigmoid; Z (f32) -> Hout staging, Rapp=sig*ph (bf16)
// MODE 2: C=H_tilde pre -> tanh; H = Z*ph + (1-Z)*Ht -> Hout
template<int NCOLS, int MODE>
__global__ __launch_bounds__(256, 3)
void gemm_kernel(const bf16* __restrict__ A,     // Abf [N][1280]
                 const bf16* __restrict__ A2,    // MODE2: Rapp [N][512] for k>=768
                 const bf16* __restrict__ W,     // WT [NCOLS][1280]
                 const float* __restrict__ bias, // [NCOLS]
                 float* __restrict__ Hout,
                 bf16* __restrict__ Rapp_out)
{
    __shared__ __align__(16) char Atile[16384];  // [128 rows][64 k] bf16, swizzled

    const int tid = threadIdx.x;
    const int w = tid >> 6, l = tid & 63;

    // T1: bijective XCD swizzle (nwg % 8 == 0 for both instantiations)
    constexpr int nb  = NCOLS / 128;
    constexpr int nwg = (N_NODES / 128) * nb;
    constexpr int cpx = nwg / 8;
    const int bid = blockIdx.x;
    const int swz = (bid & 7) * cpx + (bid >> 3);
    const int  bn = swz % nb;                    // n fastest -> A-panel L2 reuse
    const long m0 = (long)(swz / nb) * 128;
    const int  n0 = bn * 128;

    // A staging: thread covers row (r*32 + trow), granule tg; LDS dest linear
    // tid*16 per 4KB round; global src granule pre-swizzled (inverse of read).
    const int trow = tid >> 3;                   // 32 rows per round
    const int tg   = tid & 7;
    const int kes  = ((tg * 16) ^ ((trow & 7) << 4)) >> 1;

    const int wr = w >> 1, wc = w & 1;           // 2x2 wave grid
    const int lr = l & 15, lg = l >> 4;

    // B fragment base: row (n0 + wc*64 + ni*16 + lr), elems k0 + ks*32 + lg*8
    const bf16* bbase = W + (long)(n0 + wc * 64 + lr) * KTOT + lg * 8;

    f32x4 acc[4][4];
    #pragma unroll
    for (int i = 0; i < 4; ++i)
        #pragma unroll
        for (int j = 0; j < 4; ++j) acc[i][j] = f32x4{0.f, 0.f, 0.f, 0.f};

    for (int k0 = 0; k0 < KTOT; k0 += 64) {
        __syncthreads();
        const bf16* Asrc; long astr; int kofs;
        if (MODE == 2 && k0 >= D_IN) { Asrc = A2; astr = D_H;  kofs = k0 - D_IN; }
        else                         { Asrc = A;  astr = KTOT; kofs = k0; }
        #pragma unroll
        for (int r = 0; r < 4; ++r)              // A: 128 rows, 4 rounds of 32
            gload_lds16(Asrc + (m0 + r * 32 + trow) * astr + kofs + kes,
                        Atile + r * 4096 + tid * 16);

        // B: direct global->reg, L2/L1-hot weights (issued before the drain)
        bf16x8 Bf[4][2];
        #pragma unroll
        for (int ni = 0; ni < 4; ++ni)
            #pragma unroll
            for (int ks = 0; ks < 2; ++ks)
                Bf[ni][ks] = *(const bf16x8*)(bbase + (long)ni * 16 * KTOT
                                              + k0 + ks * 32);
        __syncthreads();   // vmcnt drain: A in LDS; B waited at first use

        #pragma unroll
        for (int ks = 0; ks < 2; ++ks) {
            bf16x8 af[4];
            #pragma unroll
            for (int mi = 0; mi < 4; ++mi) {
                int row = wr * 64 + mi * 16 + lr;
                int addr = (row << 7) + ((ks * 64 + lg * 16) ^ ((row & 7) << 4));
                af[mi] = *(const bf16x8*)(Atile + addr);
            }
            #pragma unroll
            for (int ni = 0; ni < 4; ++ni)
                #pragma unroll
                for (int mi = 0; mi < 4; ++mi)
                    acc[mi][ni] = __builtin_amdgcn_mfma_f32_16x16x32_bf16(
                        af[mi], Bf[ni][ks], acc[mi][ni], 0, 0, 0);
        }
    }

    // epilogue: C/D layout col = lane&15, row = (lane>>4)*4 + j   [m89 verified]
    #pragma unroll
    for (int mi = 0; mi < 4; ++mi) {
        #pragma unroll
        for (int ni = 0; ni < 4; ++ni) {
            int gc = n0 + wc * 64 + ni * 16 + lr;
            float bv = bias[gc];
            #pragma unroll
            for (int j = 0; j < 4; ++j) {
                long gr = m0 + wr * 64 + mi * 16 + lg * 4 + j;
                float v = acc[mi][ni][j] + bv;
                if (MODE == 1) {
                    float s = 1.f / (1.f + __expf(-v));
                    if (NCOLS == NG1 && n0 < D_H) {          // Z half (block-uniform)
                        Hout[gr * D_H + gc] = s;             // Z staged in f32
                    } else {
                        float ph = (float)A[gr * KTOT + D_IN + (gc - D_H)];
                        Rapp_out[gr * D_H + (gc - D_H)] = (bf16)(s * ph);
                    }
                } else {
                    float ht = 2.f / (1.f + __expf(-2.f * v)) - 1.f;   // tanh
                    long  o  = gr * D_H + gc;
                    float zz = Hout[o];
                    float ph = (float)A[gr * KTOT + D_IN + gc];
                    Hout[o] = zz * ph + (1.f - zz) * ht;
                }
            }
        }
    }
}

// ---------------- fusion: segment_sum(z) | relu(u@Wg+bg) per graph ----------
__global__ __launch_bounds__(256)
void fusion_kernel(const float* __restrict__ z, const float* __restrict__ u,
                   const float* __restrict__ Wg, const float* __restrict__ bg,
                   const int* __restrict__ batch, float* __restrict__ out)
{
    int g = blockIdx.x;
    __shared__ float us[D_U];
    __shared__ int   rng[2];
    int tid = threadIdx.x;
    if (tid < D_U) us[tid] = u[(long)g * D_U + tid];
    if (tid < 2) {
        int target = g + tid;     // lower_bound(batch, target)
        int lo = 0, hi = N_NODES;
        while (lo < hi) { int mid = (lo + hi) >> 1; if (batch[mid] < target) lo = mid + 1; else hi = mid; }
        rng[tid] = lo;
    }
    __syncthreads();
    int start = rng[0], end = rng[1];
    int d0 = tid * 2;
    float s0 = 0.f, s1 = 0.f;
    for (int n = start; n < end; ++n) {
        const float* zp = z + (long)n * D_Z + d0;
        s0 += zp[0]; s1 += zp[1];
    }
    long ob = (long)g * 1024;
    out[ob + d0]     = s0;
    out[ob + d0 + 1] = s1;
    float a0 = bg[d0], a1 = bg[d0 + 1];
    #pragma unroll 8
    for (int k = 0; k < D_U; ++k) {
        float uv = us[k];
        a0 += uv * Wg[k * D_Z + d0];
        a1 += uv * Wg[k * D_Z + d0 + 1];
    }
    out[ob + 512 + d0]     = fmaxf(a0, 0.f);
    out[ob + 512 + d0 + 1] = fmaxf(a1, 0.f);
}

// ---------------------------------------------------------------------------
extern "C" void kernel_launch(void* const* d_in, const int* in_sizes, int n_in,
                              void* d_out, int out_size, void* d_ws, size_t ws_size,
                              hipStream_t stream) {
    (void)in_sizes; (void)n_in; (void)out_size; (void)ws_size;
    const float* z      = (const float*)d_in[0];
    const float* u      = (const float*)d_in[1];
    const float* x      = (const float*)d_in[2];
    const float* prev_h = (const float*)d_in[3];
    // d_in[4] edge_index unused (K=1 ChebConv)
    const int*   batch  = (const int*)d_in[5];
    // d_in[6] batch_size == 4096 (fixed)
    const float* Wxz = (const float*)d_in[7];
    const float* bxz = (const float*)d_in[8];
    const float* Whz = (const float*)d_in[9];
    const float* bhz = (const float*)d_in[10];
    const float* Wxr = (const float*)d_in[11];
    const float* bxr = (const float*)d_in[12];
    const float* Whr = (const float*)d_in[13];
    const float* bhr = (const float*)d_in[14];
    const float* Wxh = (const float*)d_in[15];
    const float* bxh = (const float*)d_in[16];
    const float* Whh = (const float*)d_in[17];
    const float* bhh = (const float*)d_in[18];
    const float* Wg  = (const float*)d_in[19];
    const float* bg  = (const float*)d_in[20];

    char* ws = (char*)d_ws;
    bf16*  WT1   = (bf16*)ws;                                  // 2,621,440 B
    bf16*  WT2   = (bf16*)(ws + 2621440);                      // 1,310,720 B
    float* bias1 = (float*)(ws + 3932160);                     // 4 KB
    float* bias2 = (float*)(ws + 3936256);                     // 2 KB
    bf16*  Rapp  = (bf16*)(ws + 4194304);                      // 134,217,728 B
    bf16*  Abf   = (bf16*)(ws + 4194304 + 134217728);          // 335,544,320 B

    float* outF = (float*)d_out;
    float* Hout = outF + (long)N_GRAPHS * 1024;                // H region (also Z staging)

    hipLaunchKernelGGL(prep_weights, dim3(960), dim3(256), 0, stream,
                       Wxz, Whz, Wxr, Whr, Wxh, Whh,
                       bxz, bhz, bxr, bhr, bxh, bhh,
                       WT1, WT2, bias1, bias2);
    hipLaunchKernelGGL(prep_A, dim3(81920), dim3(256), 0, stream, z, x, prev_h, Abf);
    hipLaunchKernelGGL((gemm_kernel<NG1, 1>), dim3(8192), dim3(256), 0, stream,
                       Abf, (const bf16*)nullptr, WT1, bias1, Hout, Rapp);
    hipLaunchKernelGGL((gemm_kernel<D_H, 2>), dim3(4096), dim3(256), 0, stream,
                       Abf, Rapp, WT2, bias2, Hout, (bf16*)nullptr);
    hipLaunchKernelGGL(fusion_kernel, dim3(N_GRAPHS), dim3(256), 0, stream,
                       z, u, Wg, bg, batch, outF);
}

// Round 11
// 1214.129 us; speedup vs baseline: 1.2794x; 1.2794x over previous
//
#include <hip/hip_runtime.h>
#include <hip/hip_bf16.h>
#include <type_traits>

#define N_NODES 131072
#define N_GRAPHS 4096
#define D_Z 512
#define D_X 256
#define D_U 64
#define D_H 512
#define D_IN 768      // D_Z + D_X
#define KTOT 1280     // D_IN + D_H
#define NG1 1024      // two gates (Z,R) fused

using bf16   = __bf16;
using bf16x8 = __attribute__((ext_vector_type(8))) __bf16;
using f32x4  = __attribute__((ext_vector_type(4))) float;
using fl4    = __attribute__((ext_vector_type(4))) float;

__device__ __forceinline__ void gload_lds16(const void* g, void* lds) {
    __builtin_amdgcn_global_load_lds(
        (const __attribute__((address_space(1))) unsigned int*)g,
        (__attribute__((address_space(3))) unsigned int*)lds,
        16, 0, 0);
}

// ---------------- prep: weights -> bf16, transposed WT[n][k]; fused biases ---
__global__ void prep_weights(const float* __restrict__ Wxz, const float* __restrict__ Whz,
                             const float* __restrict__ Wxr, const float* __restrict__ Whr,
                             const float* __restrict__ Wxh, const float* __restrict__ Whh,
                             const float* __restrict__ bxz, const float* __restrict__ bhz,
                             const float* __restrict__ bxr, const float* __restrict__ bhr,
                             const float* __restrict__ bxh, const float* __restrict__ bhh,
                             bf16* __restrict__ WT1, bf16* __restrict__ WT2,
                             float* __restrict__ bias1, float* __restrict__ bias2)
{
    int idx = blockIdx.x * blockDim.x + threadIdx.x;
    if (idx < NG1)
        bias1[idx] = (idx < D_H) ? (bxz[idx] + bhz[idx]) : (bxr[idx - D_H] + bhr[idx - D_H]);
    if (idx < D_H)
        bias2[idx] = bxh[idx] + bhh[idx];

    const int T1 = NG1 * (KTOT / 8);
    if (idx < T1) {
        int n = idx % NG1, kc = idx / NG1, k0 = kc * 8;
        int col = (n < D_H) ? n : n - D_H;
        const float* Wx = (n < D_H) ? Wxz : Wxr;
        const float* Wh = (n < D_H) ? Whz : Whr;
        bf16x8 o;
        #pragma unroll
        for (int i = 0; i < 8; ++i) {
            int k = k0 + i;
            float f = (k < D_IN) ? Wx[(long)k * D_H + col] : Wh[(long)(k - D_IN) * D_H + col];
            o[i] = (bf16)f;
        }
        *(bf16x8*)(WT1 + (long)n * KTOT + k0) = o;
    } else {
        int j = idx - T1;               // [0, 512*160)
        int n = j % D_H, kc = j / D_H, k0 = kc * 8;
        bf16x8 o;
        #pragma unroll
        for (int i = 0; i < 8; ++i) {
            int k = k0 + i;
            float f = (k < D_IN) ? Wxh[(long)k * D_H + n] : Whh[(long)(k - D_IN) * D_H + n];
            o[i] = (bf16)f;
        }
        *(bf16x8*)(WT2 + (long)n * KTOT + k0) = o;
    }
}

// ---------------- prep: A = [z | x | prev_h] -> bf16 [N_NODES][1280] ---------
__global__ void prep_A(const float* __restrict__ z, const float* __restrict__ x,
                       const float* __restrict__ ph, bf16* __restrict__ Abf)
{
    long idx = (long)blockIdx.x * blockDim.x + threadIdx.x;   // N_NODES*160
    long row = idx / 160;
    int  e   = (int)(idx % 160) * 8;
    const float* src;
    if (e < D_Z)        src = z  + row * D_Z + e;
    else if (e < D_IN)  src = x  + row * D_X + (e - D_Z);
    else                src = ph + row * D_H + (e - D_IN);
    fl4 v0 = *(const fl4*)src;
    fl4 v1 = *(const fl4*)(src + 4);
    bf16x8 o;
    o[0]=(bf16)v0[0]; o[1]=(bf16)v0[1]; o[2]=(bf16)v0[2]; o[3]=(bf16)v0[3];
    o[4]=(bf16)v1[0]; o[5]=(bf16)v1[1]; o[6]=(bf16)v1[2]; o[7]=(bf16)v1[3];
    *(bf16x8*)(Abf + row * KTOT + e) = o;
}

// ============ GEMM 256x256 tile, BK=64, 8 waves (2Mx4N), 8-phase ============
// R11 = R4's verified schedule with the ks-INNER dependency bug fixed:
// every MFMA cluster is now ks-OUTER (8 independent MFMAs per group; the
// dependent reuse of each acc is separated by ~8 issues >= MFMA latency).
// Waits (re-verified): vmcnt(4) @P1-end guards A-hi(t) [staged P3(t-1)];
// vmcnt(2) @P3-end guards B0..B3(t+1)+AQ0,AQ2(t+1) for next P0/P1.
template<int NCOLS, int MODE>
__global__ __launch_bounds__(512, 2)
void gemm256(const bf16* __restrict__ A,     // Abf [N][1280]
             const bf16* __restrict__ A2,    // MODE2: Rapp [N][512] for k>=768
             const bf16* __restrict__ W,     // WT [NCOLS][1280]
             const float* __restrict__ bias, // [NCOLS]
             float* __restrict__ Hout,
             bf16* __restrict__ Rapp_out)
{
    __shared__ __align__(16) char Atile[2][32768];  // 256 rows x 64k bf16
    __shared__ __align__(16) char Btile[2][32768];  // 256 cols x 64k bf16

    const int tid = threadIdx.x;
    const int w = tid >> 6, l = tid & 63;
    const int wr = w >> 2, wc = w & 3;          // 2 x 4 wave grid
    const int lr = l & 15, lg = l >> 4;

    constexpr int nb  = NCOLS / 256;
    constexpr int nwg = (N_NODES / 256) * nb;
    constexpr int cpx = nwg / 8;
    const int bid = blockIdx.x;
    const int swz = (bid & 7) * cpx + (bid >> 3);
    const long m0 = (long)(swz / nb) * 256;
    const int  n0 = (swz % nb) * 256;

    // staging: one round = 8KB = 64 rows x 128B; LDS dest linear tid*16;
    // global src granule inverse-swizzled (matches swizzled ds_read).
    const int trow = tid >> 3;
    const int tg   = tid & 7;
    const int kes  = (((tg * 16) ^ ((trow & 7) << 4)) >> 1);

    const bf16* wbase  = W + (long)(n0 + trow) * KTOT + kes;
    const bf16* abase  = A + (m0 + trow) * KTOT + kes;
    const bf16* a2base = (MODE == 2) ? (A2 + (m0 + trow) * D_H + kes) : nullptr;
    char* const ldsA0 = Atile[0] + tid * 16;
    char* const ldsA1 = Atile[1] + tid * 16;
    char* const ldsB0 = Btile[0] + tid * 16;
    char* const ldsB1 = Btile[1] + tid * 16;

    constexpr int NT = KTOT / 64;   // 20 K-tiles

    auto stageB = [&](int t, int nxt, int r) {
        gload_lds16(wbase + (long)r * (64 * KTOT) + t * 64,
                    (nxt ? ldsB1 : ldsB0) + r * 8192);
    };
    auto stageA = [&](int t, int nxt, int q) {
        const int k0 = t * 64;
        const bf16* src;
        if (MODE == 2 && k0 >= D_IN) src = a2base + (long)q * (64 * D_H) + (k0 - D_IN);
        else                         src = abase  + (long)q * (64 * KTOT) + k0;
        gload_lds16(src, (nxt ? ldsA1 : ldsA0) + q * 8192);
    };
    auto ldsA = [&](int buf, int row, int ks) -> bf16x8 {
        int byte = row * 128 + ((ks * 64 + lg * 16) ^ ((row & 7) << 4));
        return *(const bf16x8*)(Atile[buf] + byte);
    };
    auto ldsB = [&](int buf, int row, int ks) -> bf16x8 {
        int byte = row * 128 + ((ks * 64 + lg * 16) ^ ((row & 7) << 4));
        return *(const bf16x8*)(Btile[buf] + byte);
    };

    f32x4 acc[8][4];
    #pragma unroll
    for (int i = 0; i < 8; ++i)
        #pragma unroll
        for (int j = 0; j < 4; ++j) acc[i][j] = f32x4{0.f, 0.f, 0.f, 0.f};

    bf16x8 af[4][2], blo[2][2], bhi[2][2];

    // ---- prologue: stage tile 0 into buf0, full drain ----
    #pragma unroll
    for (int r = 0; r < 4; ++r) stageB(0, 0, r);
    #pragma unroll
    for (int q = 0; q < 4; ++q) stageA(0, 0, q);
    asm volatile("s_waitcnt vmcnt(0)" ::: "memory");
    __builtin_amdgcn_s_barrier();

    auto step = [&](int t, auto stc) {
        constexpr bool ST = decltype(stc)::value;
        const int cur = t & 1, nxt = cur ^ 1;

        // ---- P0: (A-lo, B-lo); stage B0,B1(t+1) ----
        #pragma unroll
        for (int mi = 0; mi < 4; ++mi)
            #pragma unroll
            for (int ks = 0; ks < 2; ++ks)
                af[mi][ks] = ldsA(cur, wr * 128 + mi * 16 + lr, ks);
        #pragma unroll
        for (int ni = 0; ni < 2; ++ni)
            #pragma unroll
            for (int ks = 0; ks < 2; ++ks)
                blo[ni][ks] = ldsB(cur, wc * 64 + ni * 16 + lr, ks);
        if (ST) { stageB(t + 1, nxt, 0); stageB(t + 1, nxt, 1); }
        __builtin_amdgcn_s_barrier();
        __builtin_amdgcn_s_setprio(1);
        #pragma unroll
        for (int ks = 0; ks < 2; ++ks)          // ks OUTER: 8 independent MFMAs
            #pragma unroll
            for (int mi = 0; mi < 4; ++mi)
                #pragma unroll
                for (int ni = 0; ni < 2; ++ni)
                    acc[mi][ni] = __builtin_amdgcn_mfma_f32_16x16x32_bf16(
                        af[mi][ks], blo[ni][ks], acc[mi][ni], 0, 0, 0);
        __builtin_amdgcn_s_setprio(0);
        __builtin_amdgcn_s_barrier();

        // ---- P1: (A-lo, B-hi); stage B2,B3(t+1); vmcnt(4) ----
        #pragma unroll
        for (int ni = 0; ni < 2; ++ni)
            #pragma unroll
            for (int ks = 0; ks < 2; ++ks)
                bhi[ni][ks] = ldsB(cur, wc * 64 + (2 + ni) * 16 + lr, ks);
        if (ST) { stageB(t + 1, nxt, 2); stageB(t + 1, nxt, 3); }
        __builtin_amdgcn_s_barrier();
        __builtin_amdgcn_s_setprio(1);
        #pragma unroll
        for (int ks = 0; ks < 2; ++ks)
            #pragma unroll
            for (int mi = 0; mi < 4; ++mi)
                #pragma unroll
                for (int ni = 0; ni < 2; ++ni)
                    acc[mi][2 + ni] = __builtin_amdgcn_mfma_f32_16x16x32_bf16(
                        af[mi][ks], bhi[ni][ks], acc[mi][2 + ni], 0, 0, 0);
        __builtin_amdgcn_s_setprio(0);
        if (ST) asm volatile("s_waitcnt vmcnt(4)" ::: "memory");
        else    asm volatile("s_waitcnt vmcnt(0)" ::: "memory");
        __builtin_amdgcn_s_barrier();

        // ---- P2: (A-hi, B-hi); stage AQ0,AQ2(t+1) ----
        #pragma unroll
        for (int mi = 0; mi < 4; ++mi)
            #pragma unroll
            for (int ks = 0; ks < 2; ++ks)
                af[mi][ks] = ldsA(cur, wr * 128 + (4 + mi) * 16 + lr, ks);
        if (ST) { stageA(t + 1, nxt, 0); stageA(t + 1, nxt, 2); }
        __builtin_amdgcn_s_barrier();
        __builtin_amdgcn_s_setprio(1);
        #pragma unroll
        for (int ks = 0; ks < 2; ++ks)
            #pragma unroll
            for (int mi = 0; mi < 4; ++mi)
                #pragma unroll
                for (int ni = 0; ni < 2; ++ni)
                    acc[4 + mi][2 + ni] = __builtin_amdgcn_mfma_f32_16x16x32_bf16(
                        af[mi][ks], bhi[ni][ks], acc[4 + mi][2 + ni], 0, 0, 0);
        __builtin_amdgcn_s_setprio(0);
        __builtin_amdgcn_s_barrier();

        // ---- P3: (A-hi, B-lo); stage AQ1,AQ3(t+1); vmcnt(2) ----
        if (ST) { stageA(t + 1, nxt, 1); stageA(t + 1, nxt, 3); }
        __builtin_amdgcn_s_barrier();
        __builtin_amdgcn_s_setprio(1);
        #pragma unroll
        for (int ks = 0; ks < 2; ++ks)
            #pragma unroll
            for (int mi = 0; mi < 4; ++mi)
                #pragma unroll
                for (int ni = 0; ni < 2; ++ni)
                    acc[4 + mi][ni] = __builtin_amdgcn_mfma_f32_16x16x32_bf16(
                        af[mi][ks], blo[ni][ks], acc[4 + mi][ni], 0, 0, 0);
        __builtin_amdgcn_s_setprio(0);
        if (ST) asm volatile("s_waitcnt vmcnt(2)" ::: "memory");
        __builtin_amdgcn_s_barrier();
    };

    #pragma unroll 1
    for (int t = 0; t < NT - 1; ++t) step(t, std::true_type{});
    step(NT - 1, std::false_type{});

    // epilogue: C/D layout col = lane&15, row = (lane>>4)*4 + j
    #pragma unroll
    for (int mi = 0; mi < 8; ++mi) {
        #pragma unroll
        for (int ni = 0; ni < 4; ++ni) {
            int gc = n0 + wc * 64 + ni * 16 + lr;
            float bv = bias[gc];
            #pragma unroll
            for (int j = 0; j < 4; ++j) {
                long gr = m0 + wr * 128 + mi * 16 + lg * 4 + j;
                float v = acc[mi][ni][j] + bv;
                if (MODE == 1) {
                    float s = 1.f / (1.f + __expf(-v));
                    if (NCOLS == NG1 && n0 < D_H) {          // Z half (block-uniform)
                        Hout[gr * D_H + gc] = s;             // Z staged in f32
                    } else {
                        float ph = (float)A[gr * KTOT + D_IN + (gc - D_H)];
                        Rapp_out[gr * D_H + (gc - D_H)] = (bf16)(s * ph);
                    }
                } else {
                    float ht = 2.f / (1.f + __expf(-2.f * v)) - 1.f;   // tanh
                    long  o  = gr * D_H + gc;
                    float zz = Hout[o];
                    float ph = (float)A[gr * KTOT + D_IN + gc];
                    Hout[o] = zz * ph + (1.f - zz) * ht;
                }
            }
        }
    }
}

// ---------------- fusion: segment_sum(z) | relu(u@Wg+bg) per graph ----------
__global__ __launch_bounds__(256)
void fusion_kernel(const float* __restrict__ z, const float* __restrict__ u,
                   const float* __restrict__ Wg, const float* __restrict__ bg,
                   const int* __restrict__ batch, float* __restrict__ out)
{
    int g = blockIdx.x;
    __shared__ float us[D_U];
    __shared__ int   rng[2];
    int tid = threadIdx.x;
    if (tid < D_U) us[tid] = u[(long)g * D_U + tid];
    if (tid < 2) {
        int target = g + tid;     // lower_bound(batch, target)
        int lo = 0, hi = N_NODES;
        while (lo < hi) { int mid = (lo + hi) >> 1; if (batch[mid] < target) lo = mid + 1; else hi = mid; }
        rng[tid] = lo;
    }
    __syncthreads();
    int start = rng[0], end = rng[1];
    int d0 = tid * 2;
    float s0 = 0.f, s1 = 0.f;
    for (int n = start; n < end; ++n) {
        const float* zp = z + (long)n * D_Z + d0;
        s0 += zp[0]; s1 += zp[1];
    }
    long ob = (long)g * 1024;
    out[ob + d0]     = s0;
    out[ob + d0 + 1] = s1;
    float a0 = bg[d0], a1 = bg[d0 + 1];
    #pragma unroll 8
    for (int k = 0; k < D_U; ++k) {
        float uv = us[k];
        a0 += uv * Wg[k * D_Z + d0];
        a1 += uv * Wg[k * D_Z + d0 + 1];
    }
    out[ob + 512 + d0]     = fmaxf(a0, 0.f);
    out[ob + 512 + d0 + 1] = fmaxf(a1, 0.f);
}

// ---------------------------------------------------------------------------
extern "C" void kernel_launch(void* const* d_in, const int* in_sizes, int n_in,
                              void* d_out, int out_size, void* d_ws, size_t ws_size,
                              hipStream_t stream) {
    (void)in_sizes; (void)n_in; (void)out_size; (void)ws_size;
    const float* z      = (const float*)d_in[0];
    const float* u      = (const float*)d_in[1];
    const float* x      = (const float*)d_in[2];
    const float* prev_h = (const float*)d_in[3];
    // d_in[4] edge_index unused (K=1 ChebConv)
    const int*   batch  = (const int*)d_in[5];
    // d_in[6] batch_size == 4096 (fixed)
    const float* Wxz = (const float*)d_in[7];
    const float* bxz = (const float*)d_in[8];
    const float* Whz = (const float*)d_in[9];
    const float* bhz = (const float*)d_in[10];
    const float* Wxr = (const float*)d_in[11];
    const float* bxr = (const float*)d_in[12];
    const float* Whr = (const float*)d_in[13];
    const float* bhr = (const float*)d_in[14];
    const float* Wxh = (const float*)d_in[15];
    const float* bxh = (const float*)d_in[16];
    const float* Whh = (const float*)d_in[17];
    const float* bhh = (const float*)d_in[18];
    const float* Wg  = (const float*)d_in[19];
    const float* bg  = (const float*)d_in[20];

    char* ws = (char*)d_ws;
    bf16*  WT1   = (bf16*)ws;                                  // 2,621,440 B
    bf16*  WT2   = (bf16*)(ws + 2621440);                      // 1,310,720 B
    float* bias1 = (float*)(ws + 3932160);                     // 4 KB
    float* bias2 = (float*)(ws + 3936256);                     // 2 KB
    bf16*  Rapp  = (bf16*)(ws + 4194304);                      // 134,217,728 B
    bf16*  Abf   = (bf16*)(ws + 4194304 + 134217728);          // 335,544,320 B

    float* outF = (float*)d_out;
    float* Hout = outF + (long)N_GRAPHS * 1024;                // H region (also Z staging)

    hipLaunchKernelGGL(prep_weights, dim3(960), dim3(256), 0, stream,
                       Wxz, Whz, Wxr, Whr, Wxh, Whh,
                       bxz, bhz, bxr, bhr, bxh, bhh,
                       WT1, WT2, bias1, bias2);
    hipLaunchKernelGGL(prep_A, dim3(81920), dim3(256), 0, stream, z, x, prev_h, Abf);
    hipLaunchKernelGGL((gemm256<NG1, 1>), dim3(2048), dim3(512), 0, stream,
                       Abf, (const bf16*)nullptr, WT1, bias1, Hout, Rapp);
    hipLaunchKernelGGL((gemm256<D_H, 2>), dim3(1024), dim3(512), 0, stream,
                       Abf, Rapp, WT2, bias2, Hout, (bf16*)nullptr);
    hipLaunchKernelGGL(fusion_kernel, dim3(N_GRAPHS), dim3(256), 0, stream,
                       z, u, Wg, bg, batch, outF);
}

// Round 12
// 1069.930 us; speedup vs baseline: 1.4518x; 1.1348x over previous
//
#include <hip/hip_runtime.h>
#include <hip/hip_bf16.h>

#define N_NODES 131072
#define N_GRAPHS 4096
#define D_Z 512
#define D_X 256
#define D_U 64
#define D_H 512
#define D_IN 768      // D_Z + D_X
#define KTOT 1280     // D_IN + D_H
#define NG1 1024      // two gates (Z,R) fused

using bf16   = __bf16;
using bf16x8 = __attribute__((ext_vector_type(8))) __bf16;
using f32x4  = __attribute__((ext_vector_type(4))) float;
using fl4    = __attribute__((ext_vector_type(4))) float;

__device__ __forceinline__ void gload_lds16(const void* g, void* lds) {
    __builtin_amdgcn_global_load_lds(
        (const __attribute__((address_space(1))) unsigned int*)g,
        (__attribute__((address_space(3))) unsigned int*)lds,
        16, 0, 0);
}

// ---------------- prep: weights -> bf16, transposed WT[n][k]; fused biases ---
__global__ void prep_weights(const float* __restrict__ Wxz, const float* __restrict__ Whz,
                             const float* __restrict__ Wxr, const float* __restrict__ Whr,
                             const float* __restrict__ Wxh, const float* __restrict__ Whh,
                             const float* __restrict__ bxz, const float* __restrict__ bhz,
                             const float* __restrict__ bxr, const float* __restrict__ bhr,
                             const float* __restrict__ bxh, const float* __restrict__ bhh,
                             bf16* __restrict__ WT1, bf16* __restrict__ WT2,
                             float* __restrict__ bias1, float* __restrict__ bias2)
{
    int idx = blockIdx.x * blockDim.x + threadIdx.x;
    if (idx < NG1)
        bias1[idx] = (idx < D_H) ? (bxz[idx] + bhz[idx]) : (bxr[idx - D_H] + bhr[idx - D_H]);
    if (idx < D_H)
        bias2[idx] = bxh[idx] + bhh[idx];

    const int T1 = NG1 * (KTOT / 8);
    if (idx < T1) {
        int n = idx % NG1, kc = idx / NG1, k0 = kc * 8;
        int col = (n < D_H) ? n : n - D_H;
        const float* Wx = (n < D_H) ? Wxz : Wxr;
        const float* Wh = (n < D_H) ? Whz : Whr;
        bf16x8 o;
        #pragma unroll
        for (int i = 0; i < 8; ++i) {
            int k = k0 + i;
            float f = (k < D_IN) ? Wx[(long)k * D_H + col] : Wh[(long)(k - D_IN) * D_H + col];
            o[i] = (bf16)f;
        }
        *(bf16x8*)(WT1 + (long)n * KTOT + k0) = o;
    } else {
        int j = idx - T1;               // [0, 512*160)
        int n = j % D_H, kc = j / D_H, k0 = kc * 8;
        bf16x8 o;
        #pragma unroll
        for (int i = 0; i < 8; ++i) {
            int k = k0 + i;
            float f = (k < D_IN) ? Wxh[(long)k * D_H + n] : Whh[(long)(k - D_IN) * D_H + n];
            o[i] = (bf16)f;
        }
        *(bf16x8*)(WT2 + (long)n * KTOT + k0) = o;
    }
}

// ---------------- prep: A = [z | x | prev_h] -> bf16 [N_NODES][1280] ---------
__global__ void prep_A(const float* __restrict__ z, const float* __restrict__ x,
                       const float* __restrict__ ph, bf16* __restrict__ Abf)
{
    long idx = (long)blockIdx.x * blockDim.x + threadIdx.x;   // N_NODES*160
    long row = idx / 160;
    int  e   = (int)(idx % 160) * 8;
    const float* src;
    if (e < D_Z)        src = z  + row * D_Z + e;
    else if (e < D_IN)  src = x  + row * D_X + (e - D_Z);
    else                src = ph + row * D_H + (e - D_IN);
    fl4 v0 = *(const fl4*)src;
    fl4 v1 = *(const fl4*)(src + 4);
    bf16x8 o;
    o[0]=(bf16)v0[0]; o[1]=(bf16)v0[1]; o[2]=(bf16)v0[2]; o[3]=(bf16)v0[3];
    o[4]=(bf16)v1[0]; o[5]=(bf16)v1[1]; o[6]=(bf16)v1[2]; o[7]=(bf16)v1[3];
    *(bf16x8*)(Abf + row * KTOT + e) = o;
}

// ------------- GEMM 128x128 tile, BK=64, 4 waves (2x2), single-buffer -------
// R12 = exact R7 champion (534 us GEMM1, MfmaUtil 28.4, occ 42.7): wave-tile
// 64x64 (acc 64 regs), ks-outer MFMA, 32 KB LDS, launch_bounds(256,4),
// bijective XCD swizzle, pre-swizzled gload_lds. Only change: MODE2's K-loop
// is split into two static phases (Abf k<768 | Rapp k>=768) -> no per-tile
// pointer-select branch.
// MODE 1: C=[Z|R] -> sigmoid; Z (f32) -> Hout staging, Rapp=sig*ph (bf16)
// MODE 2: C=H_tilde pre -> tanh; H = Z*ph + (1-Z)*Ht -> Hout
template<int NCOLS, int MODE>
__global__ __launch_bounds__(256, 4)
void gemm_kernel(const bf16* __restrict__ A,     // Abf [N][1280]
                 const bf16* __restrict__ A2,    // MODE2: Rapp [N][512] for k>=768
                 const bf16* __restrict__ W,     // WT [NCOLS][1280]
                 const float* __restrict__ bias, // [NCOLS]
                 float* __restrict__ Hout,
                 bf16* __restrict__ Rapp_out)
{
    __shared__ __align__(16) char Atile[16384];  // [128 rows][64 k] bf16, swizzled
    __shared__ __align__(16) char Btile[16384];  // [128 cols][64 k] bf16, swizzled

    const int tid = threadIdx.x;
    const int w = tid >> 6, l = tid & 63;

    // T1: bijective XCD swizzle (nwg % 8 == 0 for both instantiations)
    constexpr int nb  = NCOLS / 128;
    constexpr int nwg = (N_NODES / 128) * nb;
    constexpr int cpx = nwg / 8;
    const int bid = blockIdx.x;
    const int swz = (bid & 7) * cpx + (bid >> 3);
    const int  bn = swz % nb;                    // n fastest -> A-panel L2 reuse
    const long m0 = (long)(swz / nb) * 128;
    const int  n0 = bn * 128;

    // staging: thread covers row (r*32 + trow), 16B granule tg; LDS dest is
    // linear tid*16 per 4KB round; global col pre-swizzled (inverse of read).
    const int trow = tid >> 3;                   // 32 rows per round
    const int tg   = tid & 7;
    const int kes  = ((tg * 16) ^ ((trow & 7) << 4)) >> 1;

    f32x4 acc[4][4];
    #pragma unroll
    for (int i = 0; i < 4; ++i)
        #pragma unroll
        for (int j = 0; j < 4; ++j) acc[i][j] = f32x4{0.f, 0.f, 0.f, 0.f};

    const int wr = w >> 1, wc = w & 1;           // 2x2 wave grid
    const int lr = l & 15, lg = l >> 4;

    auto do_tile = [&](int k0, const bf16* Asrc, long astr, int kofs) {
        __syncthreads();
        #pragma unroll
        for (int r = 0; r < 4; ++r)              // A: 128 rows, 4 rounds of 32
            gload_lds16(Asrc + (m0 + r * 32 + trow) * astr + kofs + kes,
                        Atile + r * 4096 + tid * 16);
        #pragma unroll
        for (int r = 0; r < 4; ++r)              // B: 128 cols, 4 rounds of 32
            gload_lds16(W + (long)(n0 + r * 32 + trow) * KTOT + k0 + kes,
                        Btile + r * 4096 + tid * 16);
        __syncthreads();   // compiler drains vmcnt before s_barrier

        #pragma unroll
        for (int ks = 0; ks < 2; ++ks) {         // ks OUTER: independent MFMAs
            bf16x8 af[4];
            #pragma unroll
            for (int mi = 0; mi < 4; ++mi) {
                int row = wr * 64 + mi * 16 + lr;
                int addr = (row << 7) + ((ks * 64 + lg * 16) ^ ((row & 7) << 4));
                af[mi] = *(const bf16x8*)(Atile + addr);
            }
            #pragma unroll
            for (int ni = 0; ni < 4; ++ni) {
                int row = wc * 64 + ni * 16 + lr;
                int addr = (row << 7) + ((ks * 64 + lg * 16) ^ ((row & 7) << 4));
                bf16x8 bfr = *(const bf16x8*)(Btile + addr);
                #pragma unroll
                for (int mi = 0; mi < 4; ++mi)
                    acc[mi][ni] = __builtin_amdgcn_mfma_f32_16x16x32_bf16(
                        af[mi], bfr, acc[mi][ni], 0, 0, 0);
            }
        }
    };

    if (MODE == 1) {
        #pragma unroll 1
        for (int k0 = 0; k0 < KTOT; k0 += 64)
            do_tile(k0, A, KTOT, k0);
    } else {
        #pragma unroll 1
        for (int k0 = 0; k0 < D_IN; k0 += 64)    // X-part from Abf
            do_tile(k0, A, KTOT, k0);
        #pragma unroll 1
        for (int k0 = D_IN; k0 < KTOT; k0 += 64) // (R*ph)-part from Rapp
            do_tile(k0, A2, D_H, k0 - D_IN);
    }

    // epilogue: C/D layout col = lane&15, row = (lane>>4)*4 + j   [m89 verified]
    #pragma unroll
    for (int mi = 0; mi < 4; ++mi) {
        #pragma unroll
        for (int ni = 0; ni < 4; ++ni) {
            int gc = n0 + wc * 64 + ni * 16 + lr;
            float bv = bias[gc];
            #pragma unroll
            for (int j = 0; j < 4; ++j) {
                long gr = m0 + wr * 64 + mi * 16 + lg * 4 + j;
                float v = acc[mi][ni][j] + bv;
                if (MODE == 1) {
                    float s = 1.f / (1.f + __expf(-v));
                    if (NCOLS == NG1 && n0 < D_H) {          // Z half (block-uniform)
                        Hout[gr * D_H + gc] = s;             // Z staged in f32
                    } else {
                        float ph = (float)A[gr * KTOT + D_IN + (gc - D_H)];
                        Rapp_out[gr * D_H + (gc - D_H)] = (bf16)(s * ph);
                    }
                } else {
                    float ht = 2.f / (1.f + __expf(-2.f * v)) - 1.f;   // tanh
                    long  o  = gr * D_H + gc;
                    float zz = Hout[o];
                    float ph = (float)A[gr * KTOT + D_IN + gc];
                    Hout[o] = zz * ph + (1.f - zz) * ht;
                }
            }
        }
    }
}

// ------ fusion: segment_sum(z from Abf bf16) | relu(u@Wg+bg) per graph ------
__global__ __launch_bounds__(256)
void fusion_kernel(const bf16* __restrict__ Abf, const float* __restrict__ u,
                   const float* __restrict__ Wg, const float* __restrict__ bg,
                   const int* __restrict__ batch, float* __restrict__ out)
{
    int g = blockIdx.x;
    __shared__ float us[D_U];
    __shared__ int   rng[2];
    int tid = threadIdx.x;
    if (tid < D_U) us[tid] = u[(long)g * D_U + tid];
    if (tid < 2) {
        int target = g + tid;     // lower_bound(batch, target)
        int lo = 0, hi = N_NODES;
        while (lo < hi) { int mid = (lo + hi) >> 1; if (batch[mid] < target) lo = mid + 1; else hi = mid; }
        rng[tid] = lo;
    }
    __syncthreads();
    int start = rng[0], end = rng[1];
    int d0 = tid * 2;
    float s0 = 0.f, s1 = 0.f;
    for (int n = start; n < end; ++n) {
        const bf16* zp = Abf + (long)n * KTOT + d0;    // z cols of Abf (bf16)
        s0 += (float)zp[0]; s1 += (float)zp[1];
    }
    long ob = (long)g * 1024;
    out[ob + d0]     = s0;
    out[ob + d0 + 1] = s1;
    float a0 = bg[d0], a1 = bg[d0 + 1];
    #pragma unroll 8
    for (int k = 0; k < D_U; ++k) {
        float uv = us[k];
        a0 += uv * Wg[k * D_Z + d0];
        a1 += uv * Wg[k * D_Z + d0 + 1];
    }
    out[ob + 512 + d0]     = fmaxf(a0, 0.f);
    out[ob + 512 + d0 + 1] = fmaxf(a1, 0.f);
}

// ---------------------------------------------------------------------------
extern "C" void kernel_launch(void* const* d_in, const int* in_sizes, int n_in,
                              void* d_out, int out_size, void* d_ws, size_t ws_size,
                              hipStream_t stream) {
    (void)in_sizes; (void)n_in; (void)out_size; (void)ws_size;
    const float* z      = (const float*)d_in[0];
    const float* u      = (const float*)d_in[1];
    const float* x      = (const float*)d_in[2];
    const float* prev_h = (const float*)d_in[3];
    // d_in[4] edge_index unused (K=1 ChebConv)
    const int*   batch  = (const int*)d_in[5];
    // d_in[6] batch_size == 4096 (fixed)
    const float* Wxz = (const float*)d_in[7];
    const float* bxz = (const float*)d_in[8];
    const float* Whz = (const float*)d_in[9];
    const float* bhz = (const float*)d_in[10];
    const float* Wxr = (const float*)d_in[11];
    const float* bxr = (const float*)d_in[12];
    const float* Whr = (const float*)d_in[13];
    const float* bhr = (const float*)d_in[14];
    const float* Wxh = (const float*)d_in[15];
    const float* bxh = (const float*)d_in[16];
    const float* Whh = (const float*)d_in[17];
    const float* bhh = (const float*)d_in[18];
    const float* Wg  = (const float*)d_in[19];
    const float* bg  = (const float*)d_in[20];

    char* ws = (char*)d_ws;
    bf16*  WT1   = (bf16*)ws;                                  // 2,621,440 B
    bf16*  WT2   = (bf16*)(ws + 2621440);                      // 1,310,720 B
    float* bias1 = (float*)(ws + 3932160);                     // 4 KB
    float* bias2 = (float*)(ws + 3936256);                     // 2 KB
    bf16*  Rapp  = (bf16*)(ws + 4194304);                      // 134,217,728 B
    bf16*  Abf   = (bf16*)(ws + 4194304 + 134217728);          // 335,544,320 B

    float* outF = (float*)d_out;
    float* Hout = outF + (long)N_GRAPHS * 1024;                // H region (also Z staging)

    hipLaunchKernelGGL(prep_weights, dim3(960), dim3(256), 0, stream,
                       Wxz, Whz, Wxr, Whr, Wxh, Whh,
                       bxz, bhz, bxr, bhr, bxh, bhh,
                       WT1, WT2, bias1, bias2);
    hipLaunchKernelGGL(prep_A, dim3(81920), dim3(256), 0, stream, z, x, prev_h, Abf);
    hipLaunchKernelGGL((gemm_kernel<NG1, 1>), dim3(8192), dim3(256), 0, stream,
                       Abf, (const bf16*)nullptr, WT1, bias1, Hout, Rapp);
    hipLaunchKernelGGL((gemm_kernel<D_H, 2>), dim3(4096), dim3(256), 0, stream,
                       Abf, Rapp, WT2, bias2, Hout, (bf16*)nullptr);
    hipLaunchKernelGGL(fusion_kernel, dim3(N_GRAPHS), dim3(256), 0, stream,
                       Abf, u, Wg, bg, batch, outF);
}